// Round 4
// baseline (420.455 us; speedup 1.0000x reference)
//
#include <hip/hip_runtime.h>
#include <stdint.h>

// T,B,I,H,K = 200,2048,128,128,4
#define T_DIM 200
#define B_DIM 2048
#define I_DIM 128
#define H_DIM 128
#define TS    32      // t rows per tile

typedef float  f32x4  __attribute__((ext_vector_type(4)));
typedef __bf16 bf16x8 __attribute__((ext_vector_type(8)));

union BF8 { ushort4 u2[2]; bf16x8 v; };

// native cast -> v_cvt_pk_bf16_f32 (RNE)
static __device__ __forceinline__ unsigned short f2bf(float f) {
    union { __bf16 b; unsigned short u; } c; c.b = (__bf16)f; return c.u;
}
static __device__ __forceinline__ float bf2f(unsigned short s) {
    union { unsigned u; float f; } c; c.u = ((unsigned)s) << 16;
    return c.f;
}
static __device__ __forceinline__ ushort4 cvt4(float4 v) {
    return make_ushort4(f2bf(v.x), f2bf(v.y), f2bf(v.z), f2bf(v.w));
}

// Persistent blocks (5/CU) + dynamic b-queue (atomic counter in d_ws) to kill
// the static-assignment load-imbalance tail (L ~ U[1,200]).
// Per-b body = round-3 known-good structure with E-phase remapped so each
// row's 8 h-group partials live in ONE wave: 3-level shfl_xor reduce, hg==0
// lane writes masked attk directly. Deletes the serial reduce phase + 2
// barriers/tile (5 -> 3). No registers held across barriers (spill lesson).
__global__ __launch_bounds__(256, 5) void fused_kernel(
    const float* __restrict__ x, const int* __restrict__ lengths,
    const float* __restrict__ w0, const float* __restrict__ w1,
    const float* __restrict__ b1, const float* __restrict__ w2,
    const float* __restrict__ w3, float* __restrict__ out,
    unsigned* __restrict__ wq)
{
    __shared__ __align__(16) unsigned short xs[TS][136];   //  8704 B
    __shared__ __align__(16) unsigned short x1s[TS][130];  //  8320 B (65 dw stride: 2-way only)
    __shared__ __align__(16) float attp[TS][36];           //  4608 B (psum / hacc2 reuse)
    __shared__ __align__(16) float attk[TS][4];            //   512 B
    __shared__ __align__(16) float ektL[H_DIM][4];         //  2048 B
    __shared__ __align__(16) float x2ls[4][H_DIM];         //  2048 B
    __shared__ __align__(16) float w0s[H_DIM];             //   512 B
    __shared__ __align__(16) unsigned short axl[4][136];   //  1088 B
    __shared__ __align__(16) unsigned short ams[4][136];   //  1088 B
    __shared__ int b_sh;
    // total ~28.9 KB -> 5 blocks/CU

    const int tid  = threadIdx.x;
    const int lane = tid & 63;
    const int wv   = tid >> 6;
    const int l15  = lane & 15;
    const int quad = lane >> 4;

    if (tid < 128) w0s[tid] = w0[tid];

    // ---- b-independent: preload w1 B-frags + bias (regs, once) ----
    bf16x8 bfr[2][4];
    float  bias[2];
    #pragma unroll
    for (int nt = 0; nt < 2; ++nt) {
        const int n = wv * 32 + nt * 16 + l15;
        bias[nt] = b1[n];
        #pragma unroll
        for (int ks = 0; ks < 4; ++ks) {
            const int kc = ks * 32 + quad * 8;
            const float4 p0 = *(const float4*)(w1 + (size_t)n * I_DIM + kc);
            const float4 p1 = *(const float4*)(w1 + (size_t)n * I_DIM + kc + 4);
            BF8 t;
            t.u2[0] = cvt4(p0);
            t.u2[1] = cvt4(p1);
            bfr[nt][ks] = t.v;
        }
    }

    const int sr0 = tid >> 5;   // phase-A row group 0..7
    const int sf4 = tid & 31;   // phase-A 16B column slot
    const int i   = tid & 127;
    const int hcol = tid & 127; // ACC h
    const int half = tid >> 7;
    // E-phase mapping: row's 8 h-groups within one wave
    const int rE  = wv * 8 + (lane >> 3);   // row 0..31
    const int hE0 = (lane & 7) * 16;        // h chunk base

    int bprev = -1;
    for (;;) {
        int b;
        if (wq) {
            if (tid == 0) b_sh = (int)atomicAdd(wq, 1u);
            __syncthreads();
            b = b_sh;
        } else {
            if (bprev >= 0) break;
            b = blockIdx.x;
        }
        if (b >= B_DIM) break;
        bprev = b;

        const int L     = lengths[b];
        const int start = (L > 4) ? (L - 4) : 0;
        const int nv    = (L < 4) ? L : 4;

        // ---- labeled-row loads issued early (consumed after psum reduce) ----
        const float* xp = x + (size_t)b * I_DIM + i;   // + t*B*I walks time
        float v0 = 0.f, v1 = 0.f, v2 = 0.f, v3 = 0.f;
        if (tid < 128) {
            v0 = xp[(size_t)(start + 0) * (B_DIM * I_DIM)];
            v1 = xp[(size_t)(start + 1) * (B_DIM * I_DIM)];
            v2 = xp[(size_t)(start + 2) * (B_DIM * I_DIM)];
            v3 = xp[(size_t)(start + 3) * (B_DIM * I_DIM)];
        }

        // ---- A: 8-way t-parallel column sums over t in [0,start) ----
        {
            const float* xq = x + (size_t)b * I_DIM + sf4 * 4;
            const size_t RS = (size_t)B_DIM * I_DIM;
            f32x4 s0 = (f32x4){0.f, 0.f, 0.f, 0.f};
            f32x4 s1 = s0, s2 = s0, s3 = s0;
            int t = sr0;
            for (; t + 24 < start; t += 32) {   // 4 independent f32x4 loads in flight
                s0 += *(const f32x4*)(xq + (size_t)(t     ) * RS);
                s1 += *(const f32x4*)(xq + (size_t)(t +  8) * RS);
                s2 += *(const f32x4*)(xq + (size_t)(t + 16) * RS);
                s3 += *(const f32x4*)(xq + (size_t)(t + 24) * RS);
            }
            for (; t < start; t += 8)
                s0 += *(const f32x4*)(xq + (size_t)t * RS);
            const f32x4 s = (s0 + s1) + (s2 + s3);
            float* psum = &attp[0][0];          // attp reused as [8][132] partials
            *(f32x4*)&psum[sr0 * 132 + sf4 * 4] = s;
        }
        __syncthreads();

        if (tid < 128) {
            const float* psum = &attp[0][0];
            float p = 0.f;
            #pragma unroll
            for (int g = 0; g < 8; ++g) p += psum[g * 132 + i];
            // labeled rows t = start..start+3 (always < T; k>=nv garbage masked later)
            const float p0 = p + v0, p1 = p0 + v1, p2 = p1 + v2, p3 = p2 + v3;
            axl[0][i] = f2bf(v0); axl[1][i] = f2bf(v1);
            axl[2][i] = f2bf(v2); axl[3][i] = f2bf(v3);
            ams[0][i] = f2bf(p0 / (float)(start + 1));
            ams[1][i] = f2bf(p1 / (float)(start + 2));
            ams[2][i] = f2bf(p2 / (float)(start + 3));
            ams[3][i] = f2bf(p3 / (float)(start + 4));
        }
        __syncthreads();

        // ---- B: mini-GEMM {x_lab, m_s}@{w2,w3}^T -> ektL=exp(-c), x2ls ----
        #pragma unroll
        for (int nt = 0; nt < 2; ++nt) {
            const int n = wv * 32 + nt * 16 + l15;
            f32x4 c1 = (f32x4){0.f, 0.f, 0.f, 0.f};
            f32x4 c2 = (f32x4){0.f, 0.f, 0.f, 0.f};
            #pragma unroll
            for (int ks = 0; ks < 4; ++ks) {
                const int kc = ks * 32 + quad * 8;
                const bf16x8 a1 = *(const bf16x8*)&axl[l15 & 3][kc];
                const bf16x8 a2 = *(const bf16x8*)&ams[l15 & 3][kc];
                const float4 q0 = *(const float4*)(w2 + (size_t)n * I_DIM + kc);
                const float4 q1 = *(const float4*)(w2 + (size_t)n * I_DIM + kc + 4);
                const float4 r0 = *(const float4*)(w3 + (size_t)n * I_DIM + kc);
                const float4 r1 = *(const float4*)(w3 + (size_t)n * I_DIM + kc + 4);
                BF8 bw2, bw3;
                bw2.u2[0] = cvt4(q0); bw2.u2[1] = cvt4(q1);
                bw3.u2[0] = cvt4(r0); bw3.u2[1] = cvt4(r1);
                c1 = __builtin_amdgcn_mfma_f32_16x16x32_bf16(a1, bw2.v, c1, 0, 0, 0);
                c2 = __builtin_amdgcn_mfma_f32_16x16x32_bf16(a2, bw3.v, c2, 0, 0, 0);
            }
            if (quad == 0) {    // D rows 0..3 = labeled k
                #pragma unroll
                for (int r = 0; r < 4; ++r) {
                    x2ls[r][n] = c1[r];
                    ektL[n][r] = __builtin_amdgcn_exp2f(-1.44269504f * (c1[r] + c2[r]));
                }
            }
        }
        __syncthreads();

        // ---- C: tile loop (3 barriers/tile) ----
        float hacc0 = 0.f, hacc1 = 0.f, hacc2v = 0.f, hacc3 = 0.f;

        for (int t0 = 0; t0 < L; t0 += TS) {
            const int nrows = (L - t0 < TS) ? (L - t0) : TS;

            // stage (zero-fill invalid rows -> everything downstream finite)
            #pragma unroll
            for (int it = 0; it < 4; ++it) {
                const int sl = tid + it * 256;          // TS*32 = 1024 slots
                const int r = sl >> 5, f4 = sl & 31;
                ushort4 w = make_ushort4(0, 0, 0, 0);
                if (r < nrows) {
                    const float4 v = *(const float4*)(
                        x + ((size_t)(t0 + r) * B_DIM + b) * I_DIM + f4 * 4);
                    w = cvt4(v);
                }
                *(ushort4*)&xs[r][f4 * 4] = w;
            }
            __syncthreads();

            // MFMA: x1 tile (32 t x 128 h), write [t][h] bf16
            #pragma unroll
            for (int mt = 0; mt < 2; ++mt) {
                bf16x8 afr[4];
                #pragma unroll
                for (int ks = 0; ks < 4; ++ks)
                    afr[ks] = *(const bf16x8*)&xs[mt * 16 + l15][ks * 32 + quad * 8];
                #pragma unroll
                for (int nt = 0; nt < 2; ++nt) {
                    f32x4 acc = (f32x4){0.f, 0.f, 0.f, 0.f};
                    #pragma unroll
                    for (int ks = 0; ks < 4; ++ks)
                        acc = __builtin_amdgcn_mfma_f32_16x16x32_bf16(
                            afr[ks], bfr[nt][ks], acc, 0, 0, 0);
                    const int h = wv * 32 + nt * 16 + l15;
                    const int tr = mt * 16 + quad * 4;
                    #pragma unroll
                    for (int r = 0; r < 4; ++r)
                        x1s[tr + r][h] = f2bf(acc[r] + bias[nt]);
                }
            }
            __syncthreads();

            // E: row rE handled by 8 lanes of ONE wave (16 h each); in-wave
            // 3-level shfl_xor h-reduction; hg==0 lane writes masked attk.
            {
                f32x4 a = (f32x4){0.f, 0.f, 0.f, 0.f};
                #pragma unroll
                for (int hh = 0; hh < 16; hh += 2) {
                    const int h = hE0 + hh;
                    const unsigned xv2 = *(const unsigned*)&x1s[rE][h];
                    const float xa = bf2f((unsigned short)(xv2 & 0xFFFFu));
                    const float xb = bf2f((unsigned short)(xv2 >> 16));
                    const float Ea = __builtin_amdgcn_exp2f(-1.44269504f * xa);
                    const float Eb = __builtin_amdgcn_exp2f(-1.44269504f * xb);
                    const f32x4 eka = *(const f32x4*)&ektL[h][0];
                    const f32x4 ekb = *(const f32x4*)&ektL[h + 1][0];
                    const float wa = w0s[h], wb = w0s[h + 1];
                    #pragma unroll
                    for (int k = 0; k < 4; ++k)
                        a[k] += wa * __builtin_amdgcn_rcpf(1.f + Ea * eka[k])
                              + wb * __builtin_amdgcn_rcpf(1.f + Eb * ekb[k]);
                }
                #pragma unroll
                for (int m = 1; m <= 4; m <<= 1)
                    #pragma unroll
                    for (int k = 0; k < 4; ++k)
                        a[k] += __shfl_xor(a[k], m);
                if ((lane & 7) == 0) {
                    const int s = t0 + rE;
                    f32x4 o;    // select-after-sum: garbage/NaN safe
                    o[0] = (0 < nv && s <= start    ) ? a[0] : 0.f;
                    o[1] = (1 < nv && s <= start + 1) ? a[1] : 0.f;
                    o[2] = (2 < nv && s <= start + 2) ? a[2] : 0.f;
                    o[3] = (3 < nv && s <= start + 3) ? a[3] : 0.f;
                    *(f32x4*)&attk[rE][0] = o;
                }
            }
            __syncthreads();

            // ACC: hacc[k][h] += sum_s att[k][s]*x1[s][h]; halves split 16+16 rows.
            // No trailing barrier: next stage touches only xs; stage/MFMA
            // barriers order the x1s/attk reuse.
            {
                const int sbase = half * 16;
                #pragma unroll
                for (int s2 = 0; s2 < 16; ++s2) {
                    const int srow = sbase + s2;
                    const f32x4 a4 = *(const f32x4*)&attk[srow][0];   // broadcast
                    const float xv = bf2f(x1s[srow][hcol]);           // row-broadcast
                    hacc0 += a4[0] * xv; hacc1 += a4[1] * xv;
                    hacc2v += a4[2] * xv; hacc3 += a4[3] * xv;
                }
            }
        }

        // ---- epilogue: combine halves via LDS (attp reuse), +x2_lab, mask, store ----
        {
            float* h2 = &attp[0][0];    // [128][4]; disjoint from attk/x1s used by ACC
            if (half == 1) {
                *(f32x4*)&h2[hcol * 4] = (f32x4){hacc0, hacc1, hacc2v, hacc3};
            }
            __syncthreads();
            if (tid < 128) {
                const f32x4 o = *(const f32x4*)&h2[hcol * 4];
                hacc0 += o[0]; hacc1 += o[1]; hacc2v += o[2]; hacc3 += o[3];
                out[((size_t)b * 4 + 0) * H_DIM + hcol] = (0 < nv) ? hacc0 + x2ls[0][hcol] : 0.f;
                out[((size_t)b * 4 + 1) * H_DIM + hcol] = (1 < nv) ? hacc1 + x2ls[1][hcol] : 0.f;
                out[((size_t)b * 4 + 2) * H_DIM + hcol] = (2 < nv) ? hacc2v + x2ls[2][hcol] : 0.f;
                out[((size_t)b * 4 + 3) * H_DIM + hcol] = (3 < nv) ? hacc3 + x2ls[3][hcol] : 0.f;
            }
        }
        // next-iteration top barrier orders attp reuse (psum) vs h2 reads
    }
}

extern "C" void kernel_launch(void* const* d_in, const int* in_sizes, int n_in,
                              void* d_out, int out_size, void* d_ws, size_t ws_size,
                              hipStream_t stream) {
    (void)in_sizes; (void)n_in; (void)out_size;
    const float* x       = (const float*)d_in[0];
    const int*   lengths = (const int*)d_in[1];
    // d_in[2] = label_len (==4, hard-coded)
    const float* w0 = (const float*)d_in[3];
    const float* w1 = (const float*)d_in[4];
    const float* b1 = (const float*)d_in[5];
    const float* w2 = (const float*)d_in[6];
    const float* w3 = (const float*)d_in[7];
    float* out = (float*)d_out;

    unsigned* wq = (d_ws != nullptr && ws_size >= sizeof(unsigned))
                       ? (unsigned*)d_ws : nullptr;
    if (wq) {
        hipMemsetAsync(wq, 0, sizeof(unsigned), stream);   // reset work queue
        fused_kernel<<<dim3(1280), 256, 0, stream>>>(      // 5 persistent blocks/CU
            x, lengths, w0, w1, b1, w2, w3, out, wq);
    } else {
        fused_kernel<<<dim3(B_DIM), 256, 0, stream>>>(
            x, lengths, w0, w1, b1, w2, w3, out, nullptr);
    }
}

// Round 5
// 386.652 us; speedup vs baseline: 1.0874x; 1.0874x over previous
//
#include <hip/hip_runtime.h>
#include <stdint.h>

// T,B,I,H,K = 200,2048,128,128,4
#define T_DIM 200
#define B_DIM 2048
#define I_DIM 128
#define H_DIM 128
#define TS    32      // t rows per tile

typedef float  f32x4  __attribute__((ext_vector_type(4)));
typedef __bf16 bf16x8 __attribute__((ext_vector_type(8)));

union BF8 { ushort4 u2[2]; bf16x8 v; };

// native cast -> v_cvt_pk_bf16_f32 (RNE)
static __device__ __forceinline__ unsigned short f2bf(float f) {
    union { __bf16 b; unsigned short u; } c; c.b = (__bf16)f; return c.u;
}
static __device__ __forceinline__ float bf2f(unsigned short s) {
    union { unsigned u; float f; } c; c.u = ((unsigned)s) << 16;
    return c.f;
}
static __device__ __forceinline__ ushort4 cvt4(float4 v) {
    return make_ushort4(f2bf(v.x), f2bf(v.y), f2bf(v.z), f2bf(v.w));
}

// ek table swizzle: 8 floats/h {ek0..ek3, w0, pad3}; base = h*8 ^ ((h>>4)*8).
// E reads h = (lane&7)*16+hh -> bank 8*((hh^(lane&7))&3): 2-way, b128-aligned.
static __device__ __forceinline__ int ekbase(int h) {
    return (h << 3) ^ ((h >> 4) << 3);
}

// Persistent blocks + dynamic b-queue (atomic in d_ws) to kill the L~U[1,200]
// static-assignment tail. launch_bounds(256,4) — round-4 lesson: bound 5 made
// the allocator chase a smaller VGPR bin and spill (~+110MB HBM traffic).
// E-phase: each row's 128 h handled by 8 lanes of ONE wave (16 h each),
// 3-level shfl_xor reduce, (lane&7)==0 writes masked attk. ek/w0 reads go
// through the XOR-swizzled ektS2 (round-4's 8-way ektL conflict fixed).
// 3 barriers/tile. No registers held across barriers (spill lesson).
__global__ __launch_bounds__(256, 4) void fused_kernel(
    const float* __restrict__ x, const int* __restrict__ lengths,
    const float* __restrict__ w0, const float* __restrict__ w1,
    const float* __restrict__ b1, const float* __restrict__ w2,
    const float* __restrict__ w3, float* __restrict__ out,
    unsigned* __restrict__ wq)
{
    __shared__ __align__(16) unsigned short xs[TS][136];   //  8704 B
    __shared__ __align__(16) unsigned short x1s[TS][130];  //  8320 B (65 dw stride: 2-way only)
    __shared__ __align__(16) float attp[TS][36];           //  4608 B (psum / hacc2 reuse)
    __shared__ __align__(16) float attk[TS][4];            //   512 B
    __shared__ __align__(16) float ektS2[H_DIM * 8];       //  4096 B (swizzled ek+w0)
    __shared__ __align__(16) float x2ls[4][H_DIM];         //  2048 B
    __shared__ __align__(16) unsigned short axl[4][136];   //  1088 B
    __shared__ __align__(16) unsigned short ams[4][136];   //  1088 B
    __shared__ int b_sh;
    // total ~30.5 KB -> LDS allows 5 blocks/CU

    const int tid  = threadIdx.x;
    const int lane = tid & 63;
    const int wv   = tid >> 6;
    const int l15  = lane & 15;
    const int quad = lane >> 4;

    // w0 into swizzled slot 4 (written once; phase B rewrites slots 0..3 only)
    if (tid < 128) ektS2[ekbase(tid) + 4] = w0[tid];

    // ---- b-independent: preload w1 B-frags + bias (regs, once) ----
    bf16x8 bfr[2][4];
    float  bias[2];
    #pragma unroll
    for (int nt = 0; nt < 2; ++nt) {
        const int n = wv * 32 + nt * 16 + l15;
        bias[nt] = b1[n];
        #pragma unroll
        for (int ks = 0; ks < 4; ++ks) {
            const int kc = ks * 32 + quad * 8;
            const float4 p0 = *(const float4*)(w1 + (size_t)n * I_DIM + kc);
            const float4 p1 = *(const float4*)(w1 + (size_t)n * I_DIM + kc + 4);
            BF8 t;
            t.u2[0] = cvt4(p0);
            t.u2[1] = cvt4(p1);
            bfr[nt][ks] = t.v;
        }
    }

    const int sr0 = tid >> 5;   // phase-A row group 0..7
    const int sf4 = tid & 31;   // phase-A 16B column slot
    const int i   = tid & 127;
    const int hcol = tid & 127; // ACC h
    const int half = tid >> 7;
    // E-phase mapping: row's 8 h-chunks within one wave
    const int rE  = wv * 8 + (lane >> 3);   // row 0..31
    const int hE0 = (lane & 7) * 16;        // h chunk base

    int bprev = -1;
    for (;;) {
        int b;
        if (wq) {
            if (tid == 0) b_sh = (int)atomicAdd(wq, 1u);
            __syncthreads();
            b = b_sh;
        } else {
            if (bprev >= 0) break;
            b = blockIdx.x;
        }
        if (b >= B_DIM) break;
        bprev = b;

        const int L     = lengths[b];
        const int start = (L > 4) ? (L - 4) : 0;
        const int nv    = (L < 4) ? L : 4;

        // ---- labeled-row loads issued early (consumed after psum reduce) ----
        const float* xp = x + (size_t)b * I_DIM + i;   // + t*B*I walks time
        float v0 = 0.f, v1 = 0.f, v2 = 0.f, v3 = 0.f;
        if (tid < 128) {
            v0 = xp[(size_t)(start + 0) * (B_DIM * I_DIM)];
            v1 = xp[(size_t)(start + 1) * (B_DIM * I_DIM)];
            v2 = xp[(size_t)(start + 2) * (B_DIM * I_DIM)];
            v3 = xp[(size_t)(start + 3) * (B_DIM * I_DIM)];
        }

        // ---- A: 8-way t-parallel column sums over t in [0,start) ----
        {
            const float* xq = x + (size_t)b * I_DIM + sf4 * 4;
            const size_t RS = (size_t)B_DIM * I_DIM;
            f32x4 s0 = (f32x4){0.f, 0.f, 0.f, 0.f};
            f32x4 s1 = s0, s2 = s0, s3 = s0;
            int t = sr0;
            for (; t + 24 < start; t += 32) {   // 4 independent f32x4 loads in flight
                s0 += *(const f32x4*)(xq + (size_t)(t     ) * RS);
                s1 += *(const f32x4*)(xq + (size_t)(t +  8) * RS);
                s2 += *(const f32x4*)(xq + (size_t)(t + 16) * RS);
                s3 += *(const f32x4*)(xq + (size_t)(t + 24) * RS);
            }
            for (; t < start; t += 8)
                s0 += *(const f32x4*)(xq + (size_t)t * RS);
            const f32x4 s = (s0 + s1) + (s2 + s3);
            float* psum = &attp[0][0];          // attp reused as [8][132] partials
            *(f32x4*)&psum[sr0 * 132 + sf4 * 4] = s;
        }
        __syncthreads();

        if (tid < 128) {
            const float* psum = &attp[0][0];
            float p = 0.f;
            #pragma unroll
            for (int g = 0; g < 8; ++g) p += psum[g * 132 + i];
            // labeled rows t = start..start+3 (always < T; k>=nv garbage masked later)
            const float p0 = p + v0, p1 = p0 + v1, p2 = p1 + v2, p3 = p2 + v3;
            axl[0][i] = f2bf(v0); axl[1][i] = f2bf(v1);
            axl[2][i] = f2bf(v2); axl[3][i] = f2bf(v3);
            ams[0][i] = f2bf(p0 / (float)(start + 1));
            ams[1][i] = f2bf(p1 / (float)(start + 2));
            ams[2][i] = f2bf(p2 / (float)(start + 3));
            ams[3][i] = f2bf(p3 / (float)(start + 4));
        }
        __syncthreads();

        // ---- B: mini-GEMM {x_lab, m_s}@{w2,w3}^T -> ektS2=exp(-c), x2ls ----
        #pragma unroll
        for (int nt = 0; nt < 2; ++nt) {
            const int n = wv * 32 + nt * 16 + l15;
            f32x4 c1 = (f32x4){0.f, 0.f, 0.f, 0.f};
            f32x4 c2 = (f32x4){0.f, 0.f, 0.f, 0.f};
            #pragma unroll
            for (int ks = 0; ks < 4; ++ks) {
                const int kc = ks * 32 + quad * 8;
                const bf16x8 a1 = *(const bf16x8*)&axl[l15 & 3][kc];
                const bf16x8 a2 = *(const bf16x8*)&ams[l15 & 3][kc];
                const float4 q0 = *(const float4*)(w2 + (size_t)n * I_DIM + kc);
                const float4 q1 = *(const float4*)(w2 + (size_t)n * I_DIM + kc + 4);
                const float4 r0 = *(const float4*)(w3 + (size_t)n * I_DIM + kc);
                const float4 r1 = *(const float4*)(w3 + (size_t)n * I_DIM + kc + 4);
                BF8 bw2, bw3;
                bw2.u2[0] = cvt4(q0); bw2.u2[1] = cvt4(q1);
                bw3.u2[0] = cvt4(r0); bw3.u2[1] = cvt4(r1);
                c1 = __builtin_amdgcn_mfma_f32_16x16x32_bf16(a1, bw2.v, c1, 0, 0, 0);
                c2 = __builtin_amdgcn_mfma_f32_16x16x32_bf16(a2, bw3.v, c2, 0, 0, 0);
            }
            if (quad == 0) {    // D rows 0..3 = labeled k
                const int eb = ekbase(n);
                #pragma unroll
                for (int r = 0; r < 4; ++r) {
                    x2ls[r][n] = c1[r];
                    ektS2[eb + r] = __builtin_amdgcn_exp2f(-1.44269504f * (c1[r] + c2[r]));
                }
            }
        }
        __syncthreads();

        // ---- C: tile loop (3 barriers/tile) ----
        float hacc0 = 0.f, hacc1 = 0.f, hacc2v = 0.f, hacc3 = 0.f;

        for (int t0 = 0; t0 < L; t0 += TS) {
            const int nrows = (L - t0 < TS) ? (L - t0) : TS;

            // stage (zero-fill invalid rows -> everything downstream finite)
            #pragma unroll
            for (int it = 0; it < 4; ++it) {
                const int sl = tid + it * 256;          // TS*32 = 1024 slots
                const int r = sl >> 5, f4 = sl & 31;
                ushort4 w = make_ushort4(0, 0, 0, 0);
                if (r < nrows) {
                    const float4 v = *(const float4*)(
                        x + ((size_t)(t0 + r) * B_DIM + b) * I_DIM + f4 * 4);
                    w = cvt4(v);
                }
                *(ushort4*)&xs[r][f4 * 4] = w;
            }
            __syncthreads();

            // MFMA: x1 tile (32 t x 128 h), write [t][h] bf16
            #pragma unroll
            for (int mt = 0; mt < 2; ++mt) {
                bf16x8 afr[4];
                #pragma unroll
                for (int ks = 0; ks < 4; ++ks)
                    afr[ks] = *(const bf16x8*)&xs[mt * 16 + l15][ks * 32 + quad * 8];
                #pragma unroll
                for (int nt = 0; nt < 2; ++nt) {
                    f32x4 acc = (f32x4){0.f, 0.f, 0.f, 0.f};
                    #pragma unroll
                    for (int ks = 0; ks < 4; ++ks)
                        acc = __builtin_amdgcn_mfma_f32_16x16x32_bf16(
                            afr[ks], bfr[nt][ks], acc, 0, 0, 0);
                    const int h = wv * 32 + nt * 16 + l15;
                    const int tr = mt * 16 + quad * 4;
                    #pragma unroll
                    for (int r = 0; r < 4; ++r)
                        x1s[tr + r][h] = f2bf(acc[r] + bias[nt]);
                }
            }
            __syncthreads();

            // E: row rE by 8 lanes of one wave (16 h each); swizzled ek reads
            // (2-way max); 3-level shfl_xor h-reduce; lane&7==0 writes attk.
            {
                f32x4 a = (f32x4){0.f, 0.f, 0.f, 0.f};
                #pragma unroll
                for (int hh = 0; hh < 16; hh += 2) {
                    const int ha = hE0 + hh;
                    const unsigned xv2 = *(const unsigned*)&x1s[rE][ha];
                    const float xa = bf2f((unsigned short)(xv2 & 0xFFFFu));
                    const float xb = bf2f((unsigned short)(xv2 >> 16));
                    const float Ea = __builtin_amdgcn_exp2f(-1.44269504f * xa);
                    const float Eb = __builtin_amdgcn_exp2f(-1.44269504f * xb);
                    const int eba = ekbase(ha), ebb = ekbase(ha + 1);
                    const f32x4 eka = *(const f32x4*)&ektS2[eba];
                    const f32x4 ekb = *(const f32x4*)&ektS2[ebb];
                    const float wa = ektS2[eba + 4], wb = ektS2[ebb + 4];
                    #pragma unroll
                    for (int k = 0; k < 4; ++k)
                        a[k] += wa * __builtin_amdgcn_rcpf(1.f + Ea * eka[k])
                              + wb * __builtin_amdgcn_rcpf(1.f + Eb * ekb[k]);
                }
                #pragma unroll
                for (int m = 1; m <= 4; m <<= 1)
                    #pragma unroll
                    for (int k = 0; k < 4; ++k)
                        a[k] += __shfl_xor(a[k], m);
                if ((lane & 7) == 0) {
                    const int s = t0 + rE;
                    f32x4 o;    // select-after-sum: garbage/NaN safe
                    o[0] = (0 < nv && s <= start    ) ? a[0] : 0.f;
                    o[1] = (1 < nv && s <= start + 1) ? a[1] : 0.f;
                    o[2] = (2 < nv && s <= start + 2) ? a[2] : 0.f;
                    o[3] = (3 < nv && s <= start + 3) ? a[3] : 0.f;
                    *(f32x4*)&attk[rE][0] = o;
                }
            }
            __syncthreads();

            // ACC: hacc[k][h] += sum_s att[k][s]*x1[s][h]; halves split 16+16 rows.
            // No trailing barrier: next stage writes only xs (not read here);
            // the post-stage barrier orders the next x1s/attk rewrites.
            {
                const int sbase = half * 16;
                #pragma unroll
                for (int s2 = 0; s2 < 16; ++s2) {
                    const int srow = sbase + s2;
                    const f32x4 a4 = *(const f32x4*)&attk[srow][0];   // broadcast
                    const float xv = bf2f(x1s[srow][hcol]);           // row-broadcast
                    hacc0 += a4[0] * xv; hacc1 += a4[1] * xv;
                    hacc2v += a4[2] * xv; hacc3 += a4[3] * xv;
                }
            }
        }

        // ---- epilogue: combine halves via LDS (attp reuse), +x2_lab, mask, store ----
        {
            float* h2 = &attp[0][0];    // [128][4]; disjoint from attk/x1s used by ACC
            if (half == 1) {
                *(f32x4*)&h2[hcol * 4] = (f32x4){hacc0, hacc1, hacc2v, hacc3};
            }
            __syncthreads();
            if (tid < 128) {
                const f32x4 o = *(const f32x4*)&h2[hcol * 4];
                hacc0 += o[0]; hacc1 += o[1]; hacc2v += o[2]; hacc3 += o[3];
                out[((size_t)b * 4 + 0) * H_DIM + hcol] = (0 < nv) ? hacc0 + x2ls[0][hcol] : 0.f;
                out[((size_t)b * 4 + 1) * H_DIM + hcol] = (1 < nv) ? hacc1 + x2ls[1][hcol] : 0.f;
                out[((size_t)b * 4 + 2) * H_DIM + hcol] = (2 < nv) ? hacc2v + x2ls[2][hcol] : 0.f;
                out[((size_t)b * 4 + 3) * H_DIM + hcol] = (3 < nv) ? hacc3 + x2ls[3][hcol] : 0.f;
            }
        }
        // loop-top queue barrier orders attp reuse (psum) vs h2 reads
    }
}

extern "C" void kernel_launch(void* const* d_in, const int* in_sizes, int n_in,
                              void* d_out, int out_size, void* d_ws, size_t ws_size,
                              hipStream_t stream) {
    (void)in_sizes; (void)n_in; (void)out_size;
    const float* x       = (const float*)d_in[0];
    const int*   lengths = (const int*)d_in[1];
    // d_in[2] = label_len (==4, hard-coded)
    const float* w0 = (const float*)d_in[3];
    const float* w1 = (const float*)d_in[4];
    const float* b1 = (const float*)d_in[5];
    const float* w2 = (const float*)d_in[6];
    const float* w3 = (const float*)d_in[7];
    float* out = (float*)d_out;

    unsigned* wq = (d_ws != nullptr && ws_size >= sizeof(unsigned))
                       ? (unsigned*)d_ws : nullptr;
    if (wq) {
        hipMemsetAsync(wq, 0, sizeof(unsigned), stream);   // reset work queue
        fused_kernel<<<dim3(1280), 256, 0, stream>>>(      // persistent, work-conserving
            x, lengths, w0, w1, b1, w2, w3, out, wq);
    } else {
        fused_kernel<<<dim3(B_DIM), 256, 0, stream>>>(
            x, lengths, w0, w1, b1, w2, w3, out, nullptr);
    }
}

// Round 6
// 353.243 us; speedup vs baseline: 1.1903x; 1.0946x over previous
//
#include <hip/hip_runtime.h>
#include <stdint.h>

// T,B,I,H,K = 200,2048,128,128,4
#define T_DIM 200
#define B_DIM 2048
#define I_DIM 128
#define H_DIM 128
#define TS    32      // t rows per tile

typedef float  f32x4  __attribute__((ext_vector_type(4)));
typedef __bf16 bf16x8 __attribute__((ext_vector_type(8)));

union BF8 { ushort4 u2[2]; bf16x8 v; };

// native cast -> v_cvt_pk_bf16_f32 (RNE)
static __device__ __forceinline__ unsigned short f2bf(float f) {
    union { __bf16 b; unsigned short u; } c; c.b = (__bf16)f; return c.u;
}
static __device__ __forceinline__ float bf2f(unsigned short s) {
    union { unsigned u; float f; } c; c.u = ((unsigned)s) << 16;
    return c.f;
}
static __device__ __forceinline__ ushort4 cvt4(float4 v) {
    return make_ushort4(f2bf(v.x), f2bf(v.y), f2bf(v.z), f2bf(v.w));
}

// ek table swizzle: 8 floats/h {ek0..ek3, w0, pad3}; base = h*8 ^ ((h>>4)*8).
// E reads h = (lane&7)*16+hh -> bank 8*((hh^(lane&7))&3): 2-way, b128-aligned.
static __device__ __forceinline__ int ekbase(int h) {
    return (h << 3) ^ ((h >> 4) << 3);
}

// One block per b, static 2048 grid (HW dispatch IS a dynamic queue — the
// round-5 persistent-block queue added atomics + cross-body live state that
// spilled ~35MB of scratch traffic for zero balance gain; reverted).
// Body: phases A (8-way t-parallel column sums), B (mini-GEMM -> ek/x2ls),
// C tile loop with 3 barriers/tile: stage -> MFMA x1 -> in-wave E (row's 8
// h-chunks in one wave, 3-level shfl_xor, lane&7==0 writes masked attk) ->
// ACC (no trailing barrier). ek/w0 reads via XOR-swizzled ektS2 (<=2-way).
// No registers held across barriers (round-1/4/5 spill lessons).
__global__ __launch_bounds__(256, 4) void fused_kernel(
    const float* __restrict__ x, const int* __restrict__ lengths,
    const float* __restrict__ w0, const float* __restrict__ w1,
    const float* __restrict__ b1, const float* __restrict__ w2,
    const float* __restrict__ w3, float* __restrict__ out)
{
    __shared__ __align__(16) unsigned short xs[TS][136];   //  8704 B
    __shared__ __align__(16) unsigned short x1s[TS][130];  //  8320 B (65 dw stride: 2-way only)
    __shared__ __align__(16) float attp[TS][36];           //  4608 B (psum / hacc2 reuse)
    __shared__ __align__(16) float attk[TS][4];            //   512 B
    __shared__ __align__(16) float ektS2[H_DIM * 8];       //  4096 B (swizzled ek+w0)
    __shared__ __align__(16) float x2ls[4][H_DIM];         //  2048 B
    __shared__ __align__(16) unsigned short axl[4][136];   //  1088 B
    __shared__ __align__(16) unsigned short ams[4][136];   //  1088 B
    // total ~30.5 KB

    const int b    = blockIdx.x;
    const int tid  = threadIdx.x;
    const int lane = tid & 63;
    const int wv   = tid >> 6;
    const int l15  = lane & 15;
    const int quad = lane >> 4;
    const int L     = lengths[b];
    const int start = (L > 4) ? (L - 4) : 0;
    const int nv    = (L < 4) ? L : 4;

    // w0 into swizzled slot 4 (phase B writes slots 0..3 only)
    if (tid < 128) ektS2[ekbase(tid) + 4] = w0[tid];

    // ---- labeled-row loads issued early (consumed after psum reduce) ----
    const int i = tid & 127;
    const float* xp = x + (size_t)b * I_DIM + i;   // + t*B*I walks time
    float v0 = 0.f, v1 = 0.f, v2 = 0.f, v3 = 0.f;
    if (tid < 128) {
        v0 = xp[(size_t)(start + 0) * (B_DIM * I_DIM)];
        v1 = xp[(size_t)(start + 1) * (B_DIM * I_DIM)];
        v2 = xp[(size_t)(start + 2) * (B_DIM * I_DIM)];
        v3 = xp[(size_t)(start + 3) * (B_DIM * I_DIM)];
    }

    // ---- preload w1 B-frags + bias (regs; independent of everything) ----
    bf16x8 bfr[2][4];
    float  bias[2];
    #pragma unroll
    for (int nt = 0; nt < 2; ++nt) {
        const int n = wv * 32 + nt * 16 + l15;
        bias[nt] = b1[n];
        #pragma unroll
        for (int ks = 0; ks < 4; ++ks) {
            const int kc = ks * 32 + quad * 8;
            const float4 p0 = *(const float4*)(w1 + (size_t)n * I_DIM + kc);
            const float4 p1 = *(const float4*)(w1 + (size_t)n * I_DIM + kc + 4);
            BF8 t;
            t.u2[0] = cvt4(p0);
            t.u2[1] = cvt4(p1);
            bfr[nt][ks] = t.v;
        }
    }

    // ---- A: 8-way t-parallel column sums over t in [0,start) ----
    const int sr0 = tid >> 5;   // 0..7
    const int sf4 = tid & 31;   // 0..31
    {
        const float* xq = x + (size_t)b * I_DIM + sf4 * 4;
        const size_t RS = (size_t)B_DIM * I_DIM;
        f32x4 s0 = (f32x4){0.f, 0.f, 0.f, 0.f};
        f32x4 s1 = s0, s2 = s0, s3 = s0;
        int t = sr0;
        for (; t + 24 < start; t += 32) {       // 4 independent f32x4 loads in flight
            s0 += *(const f32x4*)(xq + (size_t)(t     ) * RS);
            s1 += *(const f32x4*)(xq + (size_t)(t +  8) * RS);
            s2 += *(const f32x4*)(xq + (size_t)(t + 16) * RS);
            s3 += *(const f32x4*)(xq + (size_t)(t + 24) * RS);
        }
        for (; t < start; t += 8)
            s0 += *(const f32x4*)(xq + (size_t)t * RS);
        const f32x4 s = (s0 + s1) + (s2 + s3);
        float* psum = &attp[0][0];              // attp reused as [8][132] partials
        *(f32x4*)&psum[sr0 * 132 + sf4 * 4] = s;
    }
    __syncthreads();

    if (tid < 128) {
        const float* psum = &attp[0][0];
        float p = 0.f;
        #pragma unroll
        for (int g = 0; g < 8; ++g) p += psum[g * 132 + i];
        // labeled rows t = start..start+3 (always < T; k>=nv garbage masked later)
        const float p0 = p + v0, p1 = p0 + v1, p2 = p1 + v2, p3 = p2 + v3;
        axl[0][i] = f2bf(v0); axl[1][i] = f2bf(v1);
        axl[2][i] = f2bf(v2); axl[3][i] = f2bf(v3);
        ams[0][i] = f2bf(p0 / (float)(start + 1));
        ams[1][i] = f2bf(p1 / (float)(start + 2));
        ams[2][i] = f2bf(p2 / (float)(start + 3));
        ams[3][i] = f2bf(p3 / (float)(start + 4));
    }
    __syncthreads();

    // ---- B: mini-GEMM {x_lab, m_s}@{w2,w3}^T -> ektS2=exp(-c), x2ls ----
    #pragma unroll
    for (int nt = 0; nt < 2; ++nt) {
        const int n = wv * 32 + nt * 16 + l15;
        f32x4 c1 = (f32x4){0.f, 0.f, 0.f, 0.f};
        f32x4 c2 = (f32x4){0.f, 0.f, 0.f, 0.f};
        #pragma unroll
        for (int ks = 0; ks < 4; ++ks) {
            const int kc = ks * 32 + quad * 8;
            const bf16x8 a1 = *(const bf16x8*)&axl[l15 & 3][kc];
            const bf16x8 a2 = *(const bf16x8*)&ams[l15 & 3][kc];
            const float4 q0 = *(const float4*)(w2 + (size_t)n * I_DIM + kc);
            const float4 q1 = *(const float4*)(w2 + (size_t)n * I_DIM + kc + 4);
            const float4 r0 = *(const float4*)(w3 + (size_t)n * I_DIM + kc);
            const float4 r1 = *(const float4*)(w3 + (size_t)n * I_DIM + kc + 4);
            BF8 bw2, bw3;
            bw2.u2[0] = cvt4(q0); bw2.u2[1] = cvt4(q1);
            bw3.u2[0] = cvt4(r0); bw3.u2[1] = cvt4(r1);
            c1 = __builtin_amdgcn_mfma_f32_16x16x32_bf16(a1, bw2.v, c1, 0, 0, 0);
            c2 = __builtin_amdgcn_mfma_f32_16x16x32_bf16(a2, bw3.v, c2, 0, 0, 0);
        }
        if (quad == 0) {    // D rows 0..3 = labeled k
            const int eb = ekbase(n);
            #pragma unroll
            for (int r = 0; r < 4; ++r) {
                x2ls[r][n] = c1[r];
                ektS2[eb + r] = __builtin_amdgcn_exp2f(-1.44269504f * (c1[r] + c2[r]));
            }
        }
    }
    __syncthreads();

    // ---- C: tile loop (3 barriers/tile) ----
    const int hcol = tid & 127;       // ACC h
    const int half = tid >> 7;
    // E-phase mapping: row's 8 h-chunks within one wave
    const int rE  = wv * 8 + (lane >> 3);   // row 0..31
    const int hE0 = (lane & 7) * 16;        // h chunk base
    float hacc0 = 0.f, hacc1 = 0.f, hacc2v = 0.f, hacc3 = 0.f;

    for (int t0 = 0; t0 < L; t0 += TS) {
        const int nrows = (L - t0 < TS) ? (L - t0) : TS;

        // stage (zero-fill invalid rows -> everything downstream finite);
        // loads consumed immediately, nothing held across barriers (no spill)
        #pragma unroll
        for (int it = 0; it < 4; ++it) {
            const int sl = tid + it * 256;          // TS*32 = 1024 slots
            const int r = sl >> 5, f4 = sl & 31;
            ushort4 w = make_ushort4(0, 0, 0, 0);
            if (r < nrows) {
                const float4 v = *(const float4*)(
                    x + ((size_t)(t0 + r) * B_DIM + b) * I_DIM + f4 * 4);
                w = cvt4(v);
            }
            *(ushort4*)&xs[r][f4 * 4] = w;
        }
        __syncthreads();

        // MFMA: x1 tile (32 t x 128 h), write [t][h] bf16
        #pragma unroll
        for (int mt = 0; mt < 2; ++mt) {
            bf16x8 afr[4];
            #pragma unroll
            for (int ks = 0; ks < 4; ++ks)
                afr[ks] = *(const bf16x8*)&xs[mt * 16 + l15][ks * 32 + quad * 8];
            #pragma unroll
            for (int nt = 0; nt < 2; ++nt) {
                f32x4 acc = (f32x4){0.f, 0.f, 0.f, 0.f};
                #pragma unroll
                for (int ks = 0; ks < 4; ++ks)
                    acc = __builtin_amdgcn_mfma_f32_16x16x32_bf16(
                        afr[ks], bfr[nt][ks], acc, 0, 0, 0);
                const int h = wv * 32 + nt * 16 + l15;
                const int tr = mt * 16 + quad * 4;
                #pragma unroll
                for (int r = 0; r < 4; ++r)
                    x1s[tr + r][h] = f2bf(acc[r] + bias[nt]);
            }
        }
        __syncthreads();

        // E: row rE by 8 lanes of one wave (16 h each); swizzled ek reads
        // (<=2-way); 3-level shfl_xor h-reduce; lane&7==0 writes masked attk.
        {
            f32x4 a = (f32x4){0.f, 0.f, 0.f, 0.f};
            #pragma unroll
            for (int hh = 0; hh < 16; hh += 2) {
                const int ha = hE0 + hh;
                const unsigned xv2 = *(const unsigned*)&x1s[rE][ha];
                const float xa = bf2f((unsigned short)(xv2 & 0xFFFFu));
                const float xb = bf2f((unsigned short)(xv2 >> 16));
                const float Ea = __builtin_amdgcn_exp2f(-1.44269504f * xa);
                const float Eb = __builtin_amdgcn_exp2f(-1.44269504f * xb);
                const int eba = ekbase(ha), ebb = ekbase(ha + 1);
                const f32x4 eka = *(const f32x4*)&ektS2[eba];
                const f32x4 ekb = *(const f32x4*)&ektS2[ebb];
                const float wa = ektS2[eba + 4], wb = ektS2[ebb + 4];
                #pragma unroll
                for (int k = 0; k < 4; ++k)
                    a[k] += wa * __builtin_amdgcn_rcpf(1.f + Ea * eka[k])
                          + wb * __builtin_amdgcn_rcpf(1.f + Eb * ekb[k]);
            }
            #pragma unroll
            for (int m = 1; m <= 4; m <<= 1)
                #pragma unroll
                for (int k = 0; k < 4; ++k)
                    a[k] += __shfl_xor(a[k], m);
            if ((lane & 7) == 0) {
                const int s = t0 + rE;
                f32x4 o;    // select-after-sum: garbage/NaN safe
                o[0] = (0 < nv && s <= start    ) ? a[0] : 0.f;
                o[1] = (1 < nv && s <= start + 1) ? a[1] : 0.f;
                o[2] = (2 < nv && s <= start + 2) ? a[2] : 0.f;
                o[3] = (3 < nv && s <= start + 3) ? a[3] : 0.f;
                *(f32x4*)&attk[rE][0] = o;
            }
        }
        __syncthreads();

        // ACC: hacc[k][h] += sum_s att[k][s]*x1[s][h]; halves split 16+16 rows.
        // No trailing barrier: next stage writes only xs (not read here);
        // the post-stage barrier orders the next x1s/attk rewrites.
        {
            const int sbase = half * 16;
            #pragma unroll
            for (int s2 = 0; s2 < 16; ++s2) {
                const int srow = sbase + s2;
                const f32x4 a4 = *(const f32x4*)&attk[srow][0];   // broadcast
                const float xv = bf2f(x1s[srow][hcol]);           // row-broadcast
                hacc0 += a4[0] * xv; hacc1 += a4[1] * xv;
                hacc2v += a4[2] * xv; hacc3 += a4[3] * xv;
            }
        }
    }

    // ---- epilogue: combine halves via LDS (attp reuse), +x2_lab, mask, store ----
    {
        float* h2 = &attp[0][0];    // [128][4]; disjoint from attk/x1s used by ACC
        if (half == 1) {
            *(f32x4*)&h2[hcol * 4] = (f32x4){hacc0, hacc1, hacc2v, hacc3};
        }
        __syncthreads();
        if (tid < 128) {
            const f32x4 o = *(const f32x4*)&h2[hcol * 4];
            hacc0 += o[0]; hacc1 += o[1]; hacc2v += o[2]; hacc3 += o[3];
            out[((size_t)b * 4 + 0) * H_DIM + hcol] = (0 < nv) ? hacc0 + x2ls[0][hcol] : 0.f;
            out[((size_t)b * 4 + 1) * H_DIM + hcol] = (1 < nv) ? hacc1 + x2ls[1][hcol] : 0.f;
            out[((size_t)b * 4 + 2) * H_DIM + hcol] = (2 < nv) ? hacc2v + x2ls[2][hcol] : 0.f;
            out[((size_t)b * 4 + 3) * H_DIM + hcol] = (3 < nv) ? hacc3 + x2ls[3][hcol] : 0.f;
        }
    }
}

extern "C" void kernel_launch(void* const* d_in, const int* in_sizes, int n_in,
                              void* d_out, int out_size, void* d_ws, size_t ws_size,
                              hipStream_t stream) {
    (void)in_sizes; (void)n_in; (void)out_size; (void)d_ws; (void)ws_size;
    const float* x       = (const float*)d_in[0];
    const int*   lengths = (const int*)d_in[1];
    // d_in[2] = label_len (==4, hard-coded)
    const float* w0 = (const float*)d_in[3];
    const float* w1 = (const float*)d_in[4];
    const float* b1 = (const float*)d_in[5];
    const float* w2 = (const float*)d_in[6];
    const float* w3 = (const float*)d_in[7];
    float* out = (float*)d_out;

    fused_kernel<<<dim3(B_DIM), 256, 0, stream>>>(x, lengths, w0, w1, b1, w2, w3, out);
}

// Round 9
// 351.848 us; speedup vs baseline: 1.1950x; 1.0040x over previous
//
#include <hip/hip_runtime.h>
#include <stdint.h>

// T,B,I,H,K = 200,2048,128,128,4
#define T_DIM 200
#define B_DIM 2048
#define I_DIM 128
#define H_DIM 128
#define TS    32      // t rows per tile

typedef float  f32x4  __attribute__((ext_vector_type(4)));
typedef __bf16 bf16x8 __attribute__((ext_vector_type(8)));

union BF8 { ushort4 u2[2]; bf16x8 v; };

// native cast -> v_cvt_pk_bf16_f32 (RNE)
static __device__ __forceinline__ unsigned short f2bf(float f) {
    union { __bf16 b; unsigned short u; } c; c.b = (__bf16)f; return c.u;
}
static __device__ __forceinline__ float bf2f(unsigned short s) {
    union { unsigned u; float f; } c; c.u = ((unsigned)s) << 16;
    return c.f;
}
static __device__ __forceinline__ ushort4 cvt4(float4 v) {
    return make_ushort4(f2bf(v.x), f2bf(v.y), f2bf(v.z), f2bf(v.w));
}

// ek table swizzle: 8 floats/h {ek0..ek3, w0, pad3}; base = h*8 ^ ((h>>4)*8).
// E reads h = (lane&7)*16+hh -> bank 8*((hh^(lane&7))&3): 2-way, b128-aligned.
static __device__ __forceinline__ int ekbase(int h) {
    return (h << 3) ^ ((h >> 4) << 3);
}

// One block per b, static 2048 grid. LDS 30.5 -> 25.3 KB (attp deleted; psum
// and epilogue-h2 overlay xs, idle outside the tile loop) -> LDS now allows
// 6 blocks/CU (24 waves). Register contract stays round-6's proven
// __launch_bounds__(256,4): it is only a FLOOR for the allocator (compiled at
// VGPR=64, which HW-permits 8 waves/SIMD), so residency is LDS-limited at 6
// blocks — no allocator re-targeting (round-4 bin-chasing spill lesson), and
// no novel amdgpu_waves_per_eu attribute (rounds 7/8 container failures).
// Body: A (8-way t-parallel column sums), B (mini-GEMM -> ek/x2ls), C tile
// loop 3 barriers/tile: stage -> MFMA x1 -> in-wave E (8 lanes/row, 3-level
// shfl_xor, lane&7==0 writes masked attk) -> ACC (no trailing barrier).
__global__ __launch_bounds__(256, 4) void fused_kernel(
    const float* __restrict__ x, const int* __restrict__ lengths,
    const float* __restrict__ w0, const float* __restrict__ w1,
    const float* __restrict__ b1, const float* __restrict__ w2,
    const float* __restrict__ w3, float* __restrict__ out)
{
    __shared__ __align__(16) unsigned short xs[TS][136];   //  8704 B (also psum/h2 overlay)
    __shared__ __align__(16) unsigned short x1s[TS][130];  //  8320 B (65 dw stride: 2-way only)
    __shared__ __align__(16) float attk[TS][4];            //   512 B
    __shared__ __align__(16) float ektS2[H_DIM * 8];       //  4096 B (swizzled ek+w0)
    __shared__ __align__(16) float x2ls[4][H_DIM];         //  2048 B
    __shared__ __align__(16) unsigned short axl[4][136];   //  1088 B
    __shared__ __align__(16) unsigned short ams[4][136];   //  1088 B
    // total ~25.3 KB -> 6 blocks/CU

    const int b    = blockIdx.x;
    const int tid  = threadIdx.x;
    const int lane = tid & 63;
    const int wv   = tid >> 6;
    const int l15  = lane & 15;
    const int quad = lane >> 4;
    const int L     = lengths[b];
    const int start = (L > 4) ? (L - 4) : 0;
    const int nv    = (L < 4) ? L : 4;

    // w0 into swizzled slot 4 (phase B writes slots 0..3 only)
    if (tid < 128) ektS2[ekbase(tid) + 4] = w0[tid];

    // ---- labeled-row loads issued early (consumed after psum reduce) ----
    const int i = tid & 127;
    const float* xp = x + (size_t)b * I_DIM + i;   // + t*B*I walks time
    float v0 = 0.f, v1 = 0.f, v2 = 0.f, v3 = 0.f;
    if (tid < 128) {
        v0 = xp[(size_t)(start + 0) * (B_DIM * I_DIM)];
        v1 = xp[(size_t)(start + 1) * (B_DIM * I_DIM)];
        v2 = xp[(size_t)(start + 2) * (B_DIM * I_DIM)];
        v3 = xp[(size_t)(start + 3) * (B_DIM * I_DIM)];
    }

    // ---- preload w1 B-frags + bias (regs; independent of everything) ----
    bf16x8 bfr[2][4];
    float  bias[2];
    #pragma unroll
    for (int nt = 0; nt < 2; ++nt) {
        const int n = wv * 32 + nt * 16 + l15;
        bias[nt] = b1[n];
        #pragma unroll
        for (int ks = 0; ks < 4; ++ks) {
            const int kc = ks * 32 + quad * 8;
            const float4 p0 = *(const float4*)(w1 + (size_t)n * I_DIM + kc);
            const float4 p1 = *(const float4*)(w1 + (size_t)n * I_DIM + kc + 4);
            BF8 t;
            t.u2[0] = cvt4(p0);
            t.u2[1] = cvt4(p1);
            bfr[nt][ks] = t.v;
        }
    }

    // ---- A: 8-way t-parallel column sums over t in [0,start) ----
    const int sr0 = tid >> 5;   // 0..7
    const int sf4 = tid & 31;   // 0..31
    {
        const float* xq = x + (size_t)b * I_DIM + sf4 * 4;
        const size_t RS = (size_t)B_DIM * I_DIM;
        f32x4 s0 = (f32x4){0.f, 0.f, 0.f, 0.f};
        f32x4 s1 = s0, s2 = s0, s3 = s0;
        int t = sr0;
        for (; t + 24 < start; t += 32) {       // 4 independent f32x4 loads in flight
            s0 += *(const f32x4*)(xq + (size_t)(t     ) * RS);
            s1 += *(const f32x4*)(xq + (size_t)(t +  8) * RS);
            s2 += *(const f32x4*)(xq + (size_t)(t + 16) * RS);
            s3 += *(const f32x4*)(xq + (size_t)(t + 24) * RS);
        }
        for (; t < start; t += 8)
            s0 += *(const f32x4*)(xq + (size_t)t * RS);
        const f32x4 s = (s0 + s1) + (s2 + s3);
        float* psum = (float*)&xs[0][0];        // xs overlay: [8][132] partials
        *(f32x4*)&psum[sr0 * 132 + sf4 * 4] = s;
    }
    __syncthreads();

    if (tid < 128) {
        const float* psum = (const float*)&xs[0][0];
        float p = 0.f;
        #pragma unroll
        for (int g = 0; g < 8; ++g) p += psum[g * 132 + i];
        // labeled rows t = start..start+3 (always < T; k>=nv garbage masked later)
        const float p0 = p + v0, p1 = p0 + v1, p2 = p1 + v2, p3 = p2 + v3;
        axl[0][i] = f2bf(v0); axl[1][i] = f2bf(v1);
        axl[2][i] = f2bf(v2); axl[3][i] = f2bf(v3);
        ams[0][i] = f2bf(p0 / (float)(start + 1));
        ams[1][i] = f2bf(p1 / (float)(start + 2));
        ams[2][i] = f2bf(p2 / (float)(start + 3));
        ams[3][i] = f2bf(p3 / (float)(start + 4));
    }
    __syncthreads();

    // ---- B: mini-GEMM {x_lab, m_s}@{w2,w3}^T -> ektS2=exp(-c), x2ls ----
    #pragma unroll
    for (int nt = 0; nt < 2; ++nt) {
        const int n = wv * 32 + nt * 16 + l15;
        f32x4 c1 = (f32x4){0.f, 0.f, 0.f, 0.f};
        f32x4 c2 = (f32x4){0.f, 0.f, 0.f, 0.f};
        #pragma unroll
        for (int ks = 0; ks < 4; ++ks) {
            const int kc = ks * 32 + quad * 8;
            const bf16x8 a1 = *(const bf16x8*)&axl[l15 & 3][kc];
            const bf16x8 a2 = *(const bf16x8*)&ams[l15 & 3][kc];
            const float4 q0 = *(const float4*)(w2 + (size_t)n * I_DIM + kc);
            const float4 q1 = *(const float4*)(w2 + (size_t)n * I_DIM + kc + 4);
            const float4 r0 = *(const float4*)(w3 + (size_t)n * I_DIM + kc);
            const float4 r1 = *(const float4*)(w3 + (size_t)n * I_DIM + kc + 4);
            BF8 bw2, bw3;
            bw2.u2[0] = cvt4(q0); bw2.u2[1] = cvt4(q1);
            bw3.u2[0] = cvt4(r0); bw3.u2[1] = cvt4(r1);
            c1 = __builtin_amdgcn_mfma_f32_16x16x32_bf16(a1, bw2.v, c1, 0, 0, 0);
            c2 = __builtin_amdgcn_mfma_f32_16x16x32_bf16(a2, bw3.v, c2, 0, 0, 0);
        }
        if (quad == 0) {    // D rows 0..3 = labeled k
            const int eb = ekbase(n);
            #pragma unroll
            for (int r = 0; r < 4; ++r) {
                x2ls[r][n] = c1[r];
                ektS2[eb + r] = __builtin_amdgcn_exp2f(-1.44269504f * (c1[r] + c2[r]));
            }
        }
    }
    __syncthreads();

    // ---- C: tile loop (3 barriers/tile) ----
    const int hcol = tid & 127;       // ACC h
    const int half = tid >> 7;
    // E-phase mapping: row's 8 h-chunks within one wave
    const int rE  = wv * 8 + (lane >> 3);   // row 0..31
    const int hE0 = (lane & 7) * 16;        // h chunk base
    float hacc0 = 0.f, hacc1 = 0.f, hacc2v = 0.f, hacc3 = 0.f;

    for (int t0 = 0; t0 < L; t0 += TS) {
        const int nrows = (L - t0 < TS) ? (L - t0) : TS;

        // stage (zero-fill invalid rows -> everything downstream finite);
        // loads consumed immediately, nothing held across barriers (no spill)
        #pragma unroll
        for (int it = 0; it < 4; ++it) {
            const int sl = tid + it * 256;          // TS*32 = 1024 slots
            const int r = sl >> 5, f4 = sl & 31;
            ushort4 w = make_ushort4(0, 0, 0, 0);
            if (r < nrows) {
                const float4 v = *(const float4*)(
                    x + ((size_t)(t0 + r) * B_DIM + b) * I_DIM + f4 * 4);
                w = cvt4(v);
            }
            *(ushort4*)&xs[r][f4 * 4] = w;
        }
        __syncthreads();

        // MFMA: x1 tile (32 t x 128 h), write [t][h] bf16
        #pragma unroll
        for (int mt = 0; mt < 2; ++mt) {
            bf16x8 afr[4];
            #pragma unroll
            for (int ks = 0; ks < 4; ++ks)
                afr[ks] = *(const bf16x8*)&xs[mt * 16 + l15][ks * 32 + quad * 8];
            #pragma unroll
            for (int nt = 0; nt < 2; ++nt) {
                f32x4 acc = (f32x4){0.f, 0.f, 0.f, 0.f};
                #pragma unroll
                for (int ks = 0; ks < 4; ++ks)
                    acc = __builtin_amdgcn_mfma_f32_16x16x32_bf16(
                        afr[ks], bfr[nt][ks], acc, 0, 0, 0);
                const int h = wv * 32 + nt * 16 + l15;
                const int tr = mt * 16 + quad * 4;
                #pragma unroll
                for (int r = 0; r < 4; ++r)
                    x1s[tr + r][h] = f2bf(acc[r] + bias[nt]);
            }
        }
        __syncthreads();

        // E: row rE by 8 lanes of one wave (16 h each); swizzled ek reads
        // (<=2-way); 3-level shfl_xor h-reduce; lane&7==0 writes masked attk.
        {
            f32x4 a = (f32x4){0.f, 0.f, 0.f, 0.f};
            #pragma unroll
            for (int hh = 0; hh < 16; hh += 2) {
                const int ha = hE0 + hh;
                const unsigned xv2 = *(const unsigned*)&x1s[rE][ha];
                const float xa = bf2f((unsigned short)(xv2 & 0xFFFFu));
                const float xb = bf2f((unsigned short)(xv2 >> 16));
                const float Ea = __builtin_amdgcn_exp2f(-1.44269504f * xa);
                const float Eb = __builtin_amdgcn_exp2f(-1.44269504f * xb);
                const int eba = ekbase(ha), ebb = ekbase(ha + 1);
                const f32x4 eka = *(const f32x4*)&ektS2[eba];
                const f32x4 ekb = *(const f32x4*)&ektS2[ebb];
                const float wa = ektS2[eba + 4], wb = ektS2[ebb + 4];
                #pragma unroll
                for (int k = 0; k < 4; ++k)
                    a[k] += wa * __builtin_amdgcn_rcpf(1.f + Ea * eka[k])
                          + wb * __builtin_amdgcn_rcpf(1.f + Eb * ekb[k]);
            }
            #pragma unroll
            for (int m = 1; m <= 4; m <<= 1)
                #pragma unroll
                for (int k = 0; k < 4; ++k)
                    a[k] += __shfl_xor(a[k], m);
            if ((lane & 7) == 0) {
                const int s = t0 + rE;
                f32x4 o;    // select-after-sum: garbage/NaN safe
                o[0] = (0 < nv && s <= start    ) ? a[0] : 0.f;
                o[1] = (1 < nv && s <= start + 1) ? a[1] : 0.f;
                o[2] = (2 < nv && s <= start + 2) ? a[2] : 0.f;
                o[3] = (3 < nv && s <= start + 3) ? a[3] : 0.f;
                *(f32x4*)&attk[rE][0] = o;
            }
        }
        __syncthreads();

        // ACC: hacc[k][h] += sum_s att[k][s]*x1[s][h]; halves split 16+16 rows.
        // No trailing barrier: next stage writes only xs (not read here);
        // the post-stage barrier orders the next x1s/attk rewrites.
        {
            const int sbase = half * 16;
            #pragma unroll
            for (int s2 = 0; s2 < 16; ++s2) {
                const int srow = sbase + s2;
                const f32x4 a4 = *(const f32x4*)&attk[srow][0];   // broadcast
                const float xv = bf2f(x1s[srow][hcol]);           // row-broadcast
                hacc0 += a4[0] * xv; hacc1 += a4[1] * xv;
                hacc2v += a4[2] * xv; hacc3 += a4[3] * xv;
            }
        }
    }

    // ---- epilogue: combine halves via xs-overlay h2, +x2_lab, mask, store ----
    {
        float* h2 = (float*)&xs[0][0];  // [128][4]; xs idle after last MFMA read
        if (half == 1) {
            *(f32x4*)&h2[hcol * 4] = (f32x4){hacc0, hacc1, hacc2v, hacc3};
        }
        __syncthreads();
        if (tid < 128) {
            const f32x4 o = *(const f32x4*)&h2[hcol * 4];
            hacc0 += o[0]; hacc1 += o[1]; hacc2v += o[2]; hacc3 += o[3];
            out[((size_t)b * 4 + 0) * H_DIM + hcol] = (0 < nv) ? hacc0 + x2ls[0][hcol] : 0.f;
            out[((size_t)b * 4 + 1) * H_DIM + hcol] = (1 < nv) ? hacc1 + x2ls[1][hcol] : 0.f;
            out[((size_t)b * 4 + 2) * H_DIM + hcol] = (2 < nv) ? hacc2v + x2ls[2][hcol] : 0.f;
            out[((size_t)b * 4 + 3) * H_DIM + hcol] = (3 < nv) ? hacc3 + x2ls[3][hcol] : 0.f;
        }
    }
}

extern "C" void kernel_launch(void* const* d_in, const int* in_sizes, int n_in,
                              void* d_out, int out_size, void* d_ws, size_t ws_size,
                              hipStream_t stream) {
    (void)in_sizes; (void)n_in; (void)out_size; (void)d_ws; (void)ws_size;
    const float* x       = (const float*)d_in[0];
    const int*   lengths = (const int*)d_in[1];
    // d_in[2] = label_len (==4, hard-coded)
    const float* w0 = (const float*)d_in[3];
    const float* w1 = (const float*)d_in[4];
    const float* b1 = (const float*)d_in[5];
    const float* w2 = (const float*)d_in[6];
    const float* w3 = (const float*)d_in[7];
    float* out = (float*)d_out;

    fused_kernel<<<dim3(B_DIM), 256, 0, stream>>>(x, lengths, w0, w1, b1, w2, w3, out);
}